// Round 1
// baseline (526.125 us; speedup 1.0000x reference)
//
#include <hip/hip_runtime.h>
#include <hip/hip_bf16.h>
#include <math.h>

#define G 64
#define GV (G*G*G)      // 262144
#define NB 8

typedef unsigned short u16;
typedef unsigned long long U64;

__device__ __forceinline__ float bf2f(u16 h) {
    union { unsigned int u; float f; } c; c.u = ((unsigned int)h) << 16; return c.f;
}
__device__ __forceinline__ u16 f2bf(float f) {
    union { float f; unsigned int u; } c; c.f = f;
    unsigned int u = c.u;
    return (u16)((u + 0x7fffu + ((u >> 16) & 1u)) >> 16);   // RNE
}

// ---------------------------------------------------------------------------
// Kernel A: fused conv1(1->64) + ReLU + w2-projection onto 27 conv2 taps.
// Per voxel v: y1_c = relu(b1_c + sum_s w1[c,s]*x(v+d_s)) computed in regs,
// z_t(v) = sum_c w2[c,t]*y1_c  -> bf16. Weights are wave-uniform -> s_load.
// ---------------------------------------------------------------------------
__global__ __launch_bounds__(256) void convA_kernel(
    const float* __restrict__ bnd,   // [GV] one batch slice
    const float* __restrict__ w1,    // [64*27]
    const float* __restrict__ b1,    // [64]
    const float* __restrict__ w2,    // [64*27]
    u16* __restrict__ zbuf)          // [27*GV]
{
    int v  = blockIdx.x * 256 + threadIdx.x;
    int zc = v >> 12, yc = (v >> 6) & 63, xc = v & 63;

    float xs[27];
#pragma unroll
    for (int dz = -1; dz <= 1; dz++)
#pragma unroll
    for (int dy = -1; dy <= 1; dy++)
#pragma unroll
    for (int dx = -1; dx <= 1; dx++) {
        int s = (dz + 1) * 9 + (dy + 1) * 3 + (dx + 1);
        int zz = zc + dz, yy = yc + dy, xx = xc + dx;
        bool ok = ((unsigned)zz < (unsigned)G) & ((unsigned)yy < (unsigned)G) &
                  ((unsigned)xx < (unsigned)G);
        xs[s] = ok ? bnd[(zz << 12) + (yy << 6) + xx] : 0.0f;
    }

    float acc[27];
#pragma unroll
    for (int t = 0; t < 27; t++) acc[t] = 0.0f;

    for (int c = 0; c < 64; c++) {
        float y = b1[c];
#pragma unroll
        for (int s = 0; s < 27; s++) y = fmaf(w1[c * 27 + s], xs[s], y);
        y = fmaxf(y, 0.0f);
#pragma unroll
        for (int t = 0; t < 27; t++) acc[t] = fmaf(w2[c * 27 + t], y, acc[t]);
    }

#pragma unroll
    for (int t = 0; t < 27; t++) zbuf[t * GV + v] = f2bf(acc[t]);
}

// ---------------------------------------------------------------------------
// Kernel B: conv2 tap-stencil: x2(v) = relu(b2 + sum_t z_t(v + d_t))
// ---------------------------------------------------------------------------
__global__ __launch_bounds__(256) void convB_kernel(
    const u16* __restrict__ zbuf, const float* __restrict__ b2,
    float* __restrict__ xout)
{
    int v  = blockIdx.x * 256 + threadIdx.x;
    int zc = v >> 12, yc = (v >> 6) & 63, xc = v & 63;
    float acc = b2[0];
#pragma unroll
    for (int dz = -1; dz <= 1; dz++)
#pragma unroll
    for (int dy = -1; dy <= 1; dy++)
#pragma unroll
    for (int dx = -1; dx <= 1; dx++) {
        int t = (dz + 1) * 9 + (dy + 1) * 3 + (dx + 1);
        int zz = zc + dz, yy = yc + dy, xx = xc + dx;
        bool ok = ((unsigned)zz < (unsigned)G) & ((unsigned)yy < (unsigned)G) &
                  ((unsigned)xx < (unsigned)G);
        if (ok) acc += bf2f(zbuf[t * GV + (zz << 12) + (yy << 6) + xx]);
    }
    xout[v] = fmaxf(acc, 0.0f);
}

// ---------------------------------------------------------------------------
// fc1 partial sums: block (j, ch) does W[j, ch*4096 .. +4096) x all 8 batches
// pacc layout: [ch][b][j]  (coalesced read in fc_final)
// ---------------------------------------------------------------------------
__global__ __launch_bounds__(256) void fc1_partial_kernel(
    const float* __restrict__ W, const float* __restrict__ x,
    float* __restrict__ pacc)
{
    int j = blockIdx.x;     // 0..255
    int ch = blockIdx.y;    // 0..63
    int tid = threadIdx.x;
    int v0 = ch * 4096;

    float acc[NB];
#pragma unroll
    for (int b = 0; b < NB; b++) acc[b] = 0.0f;

    const float4* W4 = reinterpret_cast<const float4*>(W + (size_t)j * GV + v0);
    for (int i = 0; i < 4; i++) {
        int e = i * 256 + tid;            // float4 index within the 4096 chunk
        float4 w = W4[e];
#pragma unroll
        for (int b = 0; b < NB; b++) {
            float4 xv = *reinterpret_cast<const float4*>(x + (size_t)b * GV + v0 + e * 4);
            acc[b] = fmaf(w.x, xv.x, acc[b]);
            acc[b] = fmaf(w.y, xv.y, acc[b]);
            acc[b] = fmaf(w.z, xv.z, acc[b]);
            acc[b] = fmaf(w.w, xv.w, acc[b]);
        }
    }

    int lane = tid & 63, wid = tid >> 6;
#pragma unroll
    for (int b = 0; b < NB; b++)
#pragma unroll
        for (int off = 32; off > 0; off >>= 1)
            acc[b] += __shfl_down(acc[b], off, 64);

    __shared__ float sred[4][NB];
    if (lane == 0) {
#pragma unroll
        for (int b = 0; b < NB; b++) sred[wid][b] = acc[b];
    }
    __syncthreads();
    if (tid < NB) {
        float s = sred[0][tid] + sred[1][tid] + sred[2][tid] + sred[3][tid];
        pacc[(ch * NB + tid) * 256 + j] = s;
    }
}

// ---------------------------------------------------------------------------
// fc_final: sum chunks, +fc1_b, relu, dot with fc2_w, +fc2_b, sigmoid*100
// ---------------------------------------------------------------------------
__global__ __launch_bounds__(256) void fc_final_kernel(
    const float* __restrict__ pacc, const float* __restrict__ fc1_b,
    const float* __restrict__ fc2_w, const float* __restrict__ fc2_b,
    float* __restrict__ prob)
{
    int j = threadIdx.x;
    float h[NB];
#pragma unroll
    for (int b = 0; b < NB; b++) h[b] = 0.0f;
    for (int ch = 0; ch < 64; ch++) {
#pragma unroll
        for (int b = 0; b < NB; b++)
            h[b] += pacc[(ch * NB + b) * 256 + j];
    }
    float w2j = fc2_w[j];
    float contrib[NB];
#pragma unroll
    for (int b = 0; b < NB; b++)
        contrib[b] = fmaxf(h[b] + fc1_b[j], 0.0f) * w2j;

    int lane = j & 63, wid = j >> 6;
#pragma unroll
    for (int b = 0; b < NB; b++)
#pragma unroll
        for (int off = 32; off > 0; off >>= 1)
            contrib[b] += __shfl_down(contrib[b], off, 64);

    __shared__ float sred[4][NB];
    if (lane == 0) {
#pragma unroll
        for (int b = 0; b < NB; b++) sred[wid][b] = contrib[b];
    }
    __syncthreads();
    if (j < NB) {
        float t = sred[0][j] + sred[1][j] + sred[2][j] + sred[3][j] + fc2_b[0];
        prob[j] = 100.0f / (1.0f + expf(-t));
    }
}

// ---------------------------------------------------------------------------
// points: zero the field, then exact top-10 of noise (free cells) per batch.
// Keys packed as (f32 bits << 32)|idx  (noise>=0 -> monotone u64 ordering).
// ---------------------------------------------------------------------------
__global__ __launch_bounds__(256) void zero_pts_kernel(float4* __restrict__ out)
{
    out[blockIdx.x * 256 + threadIdx.x] = make_float4(0.f, 0.f, 0.f, 0.f);
}

#define BPB 32   // blocks per batch in stage 1

__global__ __launch_bounds__(256) void topk1_kernel(
    const float* __restrict__ bnd, const float* __restrict__ noise,
    U64* __restrict__ cand)
{
    int blk = blockIdx.x;     // 0..BPB-1
    int b   = blockIdx.y;
    int tid = threadIdx.x;
    int vbase = blk * (GV / BPB);
    const float* bd = bnd + (size_t)b * GV + vbase;
    const float* nz = noise + (size_t)b * GV + vbase;

    U64 top[10];
#pragma unroll
    for (int k = 0; k < 10; k++) top[k] = 0ull;

    for (int i = 0; i < (GV / BPB) / 256; i++) {    // 32 iterations
        int e = i * 256 + tid;
        float bv = bd[e];
        float s  = nz[e];
        U64 p = (bv > 0.5f) ? 0ull
              : ((((U64)__float_as_uint(s)) << 32) | (unsigned)(vbase + e));
        if (p > top[9]) {
#pragma unroll
            for (int k = 0; k < 10; k++) {
                U64 mx = p > top[k] ? p : top[k];
                U64 mn = p > top[k] ? top[k] : p;
                top[k] = mx; p = mn;
            }
        }
    }

    __shared__ U64 lcand[256 * 10];
    __shared__ U64 rv[256];
    __shared__ int rp[256];
#pragma unroll
    for (int k = 0; k < 10; k++) lcand[tid * 10 + k] = top[k];
    __syncthreads();

    for (int pass = 0; pass < 10; pass++) {
        U64 bv = 0; int bp = 0;
        for (int i = tid; i < 2560; i += 256) {
            U64 xv = lcand[i];
            if (xv > bv) { bv = xv; bp = i; }
        }
        rv[tid] = bv; rp[tid] = bp;
        __syncthreads();
        for (int off = 128; off > 0; off >>= 1) {
            if (tid < off) {
                if (rv[tid + off] > rv[tid]) { rv[tid] = rv[tid + off]; rp[tid] = rp[tid + off]; }
            }
            __syncthreads();
        }
        if (tid == 0) {
            cand[((size_t)b * BPB + blk) * 10 + pass] = rv[0];
            lcand[rp[0]] = 0ull;
        }
        __syncthreads();
    }
}

__global__ __launch_bounds__(256) void topk2_kernel(
    const U64* __restrict__ cand, float* __restrict__ pts)
{
    int b = blockIdx.x, tid = threadIdx.x;
    __shared__ U64 lc[BPB * 10];
    __shared__ U64 rv[256];
    __shared__ int rp[256];
    __shared__ int widx[10];
    for (int i = tid; i < BPB * 10; i += 256) lc[i] = cand[(size_t)b * BPB * 10 + i];
    __syncthreads();

    for (int pass = 0; pass < 10; pass++) {
        U64 bv = 0; int bp = 0;
        for (int i = tid; i < BPB * 10; i += 256) {
            U64 xv = lc[i];
            if (xv > bv) { bv = xv; bp = i; }
        }
        rv[tid] = bv; rp[tid] = bp;
        __syncthreads();
        for (int off = 128; off > 0; off >>= 1) {
            if (tid < off) {
                if (rv[tid + off] > rv[tid]) { rv[tid] = rv[tid + off]; rp[tid] = rp[tid + off]; }
            }
            __syncthreads();
        }
        if (tid == 0) { widx[pass] = (int)(rv[0] & 0xffffffffu); lc[rp[0]] = 0ull; }
        __syncthreads();
    }
    if (tid < 10) pts[(size_t)b * GV + widx[tid]] = 1.0f;
}

// ---------------------------------------------------------------------------
extern "C" void kernel_launch(void* const* d_in, const int* in_sizes, int n_in,
                              void* d_out, int out_size, void* d_ws, size_t ws_size,
                              hipStream_t stream)
{
    const float* bnd   = (const float*)d_in[0];
    const float* w1    = (const float*)d_in[1];
    const float* b1    = (const float*)d_in[2];
    const float* w2    = (const float*)d_in[3];
    const float* b2    = (const float*)d_in[4];
    const float* fw1   = (const float*)d_in[5];
    const float* fb1   = (const float*)d_in[6];
    const float* fw2   = (const float*)d_in[7];
    const float* fb2   = (const float*)d_in[8];
    const float* noise = (const float*)d_in[9];

    float* out = (float*)d_out;
    char* ws = (char*)d_ws;
    u16*   zbuf = (u16*)ws;                                   // 27*GV*2  = 13.5 MB
    float* xbuf = (float*)(ws + (size_t)27 * GV * 2);         // 8*GV*4   =  8 MB
    float* pacc = (float*)(ws + (size_t)27 * GV * 2 + (size_t)NB * GV * 4);  // 512 KB
    U64*   cand = (U64*)(ws + (size_t)27 * GV * 2 + (size_t)NB * GV * 4 + 64 * NB * 256 * 4);

    // fused conv1 + w2-projection, then 27-tap stencil, per batch (z reused)
    for (int b = 0; b < NB; b++) {
        convA_kernel<<<GV / 256, 256, 0, stream>>>(bnd + (size_t)b * GV, w1, b1, w2, zbuf);
        convB_kernel<<<GV / 256, 256, 0, stream>>>(zbuf, b2, xbuf + (size_t)b * GV);
    }

    // fc1 (memory-bound on 268 MB weight read) + fc2/sigmoid
    dim3 g1(256, 64);
    fc1_partial_kernel<<<g1, 256, 0, stream>>>(fw1, xbuf, pacc);
    fc_final_kernel<<<1, 256, 0, stream>>>(pacc, fb1, fw2, fb2, out + (size_t)NB * GV);

    // points output: zero + exact top-10 scatter
    zero_pts_kernel<<<(NB * GV / 4) / 256, 256, 0, stream>>>((float4*)out);
    dim3 gt(BPB, NB);
    topk1_kernel<<<gt, 256, 0, stream>>>(bnd, noise, cand);
    topk2_kernel<<<NB, 256, 0, stream>>>(cand, out);
}

// Round 2
// 361.816 us; speedup vs baseline: 1.4541x; 1.4541x over previous
//
#include <hip/hip_runtime.h>
#include <hip/hip_bf16.h>
#include <math.h>

#define G 64
#define GV (G*G*G)      // 262144
#define NB 8

typedef unsigned short u16;
typedef unsigned long long U64;

__device__ __forceinline__ float bf2f(u16 h) {
    union { unsigned int u; float f; } c; c.u = ((unsigned int)h) << 16; return c.f;
}
__device__ __forceinline__ u16 f2bf(float f) {
    union { float f; unsigned int u; } c; c.f = f;
    unsigned int u = c.u;
    return (u16)((u + 0x7fffu + ((u >> 16) & 1u)) >> 16);   // RNE
}

// ---------------------------------------------------------------------------
// Kernel A: fused conv1(1->64) + ReLU + w2-projection onto 27 conv2 taps.
// 3 independent FMA chains per channel to break the 27-deep latency chain.
// blockIdx.y = batch (stride params allow batched or per-batch launch).
// ---------------------------------------------------------------------------
__global__ __launch_bounds__(256) void convA_kernel(
    const float* __restrict__ bnd, size_t bnd_bs,
    u16* __restrict__ zbuf, size_t z_bs,
    const float* __restrict__ w1, const float* __restrict__ b1,
    const float* __restrict__ w2)
{
    int b = blockIdx.y;
    const float* bd = bnd + (size_t)b * bnd_bs;
    u16* zb = zbuf + (size_t)b * z_bs;

    int v  = blockIdx.x * 256 + threadIdx.x;
    int zc = v >> 12, yc = (v >> 6) & 63, xc = v & 63;

    float xs[27];
#pragma unroll
    for (int dz = -1; dz <= 1; dz++)
#pragma unroll
    for (int dy = -1; dy <= 1; dy++)
#pragma unroll
    for (int dx = -1; dx <= 1; dx++) {
        int s = (dz + 1) * 9 + (dy + 1) * 3 + (dx + 1);
        int zz = zc + dz, yy = yc + dy, xx = xc + dx;
        bool ok = ((unsigned)zz < (unsigned)G) & ((unsigned)yy < (unsigned)G) &
                  ((unsigned)xx < (unsigned)G);
        xs[s] = ok ? bd[(zz << 12) + (yy << 6) + xx] : 0.0f;
    }

    float acc[27];
#pragma unroll
    for (int t = 0; t < 27; t++) acc[t] = 0.0f;

    for (int c = 0; c < 64; c++) {
        float y0 = b1[c], y1 = 0.0f, y2 = 0.0f;
#pragma unroll
        for (int s = 0; s < 9; s++)  y0 = fmaf(w1[c * 27 + s], xs[s], y0);
#pragma unroll
        for (int s = 9; s < 18; s++) y1 = fmaf(w1[c * 27 + s], xs[s], y1);
#pragma unroll
        for (int s = 18; s < 27; s++) y2 = fmaf(w1[c * 27 + s], xs[s], y2);
        float y = fmaxf(y0 + y1 + y2, 0.0f);
#pragma unroll
        for (int t = 0; t < 27; t++) acc[t] = fmaf(w2[c * 27 + t], y, acc[t]);
    }

#pragma unroll
    for (int t = 0; t < 27; t++) zb[(size_t)t * GV + v] = f2bf(acc[t]);
}

// ---------------------------------------------------------------------------
// Kernel B: conv2 tap-stencil: x2(v) = relu(b2 + sum_t z_t(v + d_t))
// ---------------------------------------------------------------------------
__global__ __launch_bounds__(256) void convB_kernel(
    const u16* __restrict__ zbuf, size_t z_bs,
    float* __restrict__ xout, size_t x_bs,
    const float* __restrict__ b2)
{
    int b = blockIdx.y;
    const u16* zb = zbuf + (size_t)b * z_bs;
    float* xo = xout + (size_t)b * x_bs;

    int v  = blockIdx.x * 256 + threadIdx.x;
    int zc = v >> 12, yc = (v >> 6) & 63, xc = v & 63;
    float acc = b2[0];
#pragma unroll
    for (int dz = -1; dz <= 1; dz++)
#pragma unroll
    for (int dy = -1; dy <= 1; dy++)
#pragma unroll
    for (int dx = -1; dx <= 1; dx++) {
        int t = (dz + 1) * 9 + (dy + 1) * 3 + (dx + 1);
        int zz = zc + dz, yy = yc + dy, xx = xc + dx;
        bool ok = ((unsigned)zz < (unsigned)G) & ((unsigned)yy < (unsigned)G) &
                  ((unsigned)xx < (unsigned)G);
        if (ok) acc += bf2f(zb[(size_t)t * GV + (zz << 12) + (yy << 6) + xx]);
    }
    xo[v] = fmaxf(acc, 0.0f);
}

// ---------------------------------------------------------------------------
// fc1: block (jt, vc) handles 4 rows j0..j0+3 x 4096-v chunk, all 8 batches.
// Each x float4 feeds 4 W rows; epilogue via LDS transpose reduction.
// pacc layout: [b][vc][j]
// ---------------------------------------------------------------------------
__global__ __launch_bounds__(256) void fc1_kernel(
    const float* __restrict__ W, const float* __restrict__ x,
    float* __restrict__ pacc)
{
    int jt = blockIdx.x;            // 0..63
    int vc = blockIdx.y;            // 0..63
    int tid = threadIdx.x;
    int j0 = jt * 4;
    size_t v0 = (size_t)vc * 4096;

    const float4* Wp[4];
#pragma unroll
    for (int jj = 0; jj < 4; jj++)
        Wp[jj] = reinterpret_cast<const float4*>(W + (size_t)(j0 + jj) * GV + v0);
    const float4* Xp[NB];
#pragma unroll
    for (int b = 0; b < NB; b++)
        Xp[b] = reinterpret_cast<const float4*>(x + (size_t)b * GV + v0);

    float acc[4][NB];
#pragma unroll
    for (int jj = 0; jj < 4; jj++)
#pragma unroll
        for (int b = 0; b < NB; b++) acc[jj][b] = 0.0f;

    for (int i = 0; i < 4; i++) {
        int e = i * 256 + tid;
        float4 wv[4];
#pragma unroll
        for (int jj = 0; jj < 4; jj++) wv[jj] = Wp[jj][e];
#pragma unroll
        for (int b = 0; b < NB; b++) {
            float4 xv = Xp[b][e];
#pragma unroll
            for (int jj = 0; jj < 4; jj++) {
                acc[jj][b] = fmaf(wv[jj].x, xv.x, acc[jj][b]);
                acc[jj][b] = fmaf(wv[jj].y, xv.y, acc[jj][b]);
                acc[jj][b] = fmaf(wv[jj].z, xv.z, acc[jj][b]);
                acc[jj][b] = fmaf(wv[jj].w, xv.w, acc[jj][b]);
            }
        }
    }

    // Epilogue: reduce 32 outputs (j' x b) over 256 threads via LDS.
    __shared__ float sacc[256][36];     // 36-float rows: 16B-aligned, bank-spread
    float4* row = reinterpret_cast<float4*>(&sacc[tid][0]);
#pragma unroll
    for (int jj = 0; jj < 4; jj++) {
        row[jj * 2 + 0] = make_float4(acc[jj][0], acc[jj][1], acc[jj][2], acc[jj][3]);
        row[jj * 2 + 1] = make_float4(acc[jj][4], acc[jj][5], acc[jj][6], acc[jj][7]);
    }
    __syncthreads();

    __shared__ float p2[8][40];
    {
        int o = tid & 31, g = tid >> 5;
        float s = 0.0f;
#pragma unroll
        for (int k = 0; k < 32; k++) s += sacc[g * 32 + k][o];
        p2[g][o] = s;
    }
    __syncthreads();
    if (tid < 32) {
        float s = 0.0f;
#pragma unroll
        for (int g = 0; g < 8; g++) s += p2[g][tid];
        int jj = tid >> 3, b = tid & 7;
        pacc[((size_t)b * 64 + vc) * 256 + (j0 + jj)] = s;
    }
}

// ---------------------------------------------------------------------------
// fc_final: sum chunks, +fc1_b, relu, dot with fc2_w, +fc2_b, sigmoid*100
// pacc layout: [b][vc=64][j=256]
// ---------------------------------------------------------------------------
__global__ __launch_bounds__(256) void fc_final_kernel(
    const float* __restrict__ pacc, const float* __restrict__ fc1_b,
    const float* __restrict__ fc2_w, const float* __restrict__ fc2_b,
    float* __restrict__ prob)
{
    int j = threadIdx.x;
    float h[NB];
#pragma unroll
    for (int b = 0; b < NB; b++) h[b] = 0.0f;
    for (int c = 0; c < 64; c++) {
#pragma unroll
        for (int b = 0; b < NB; b++)
            h[b] += pacc[((size_t)b * 64 + c) * 256 + j];
    }
    float w2j = fc2_w[j];
    float contrib[NB];
#pragma unroll
    for (int b = 0; b < NB; b++)
        contrib[b] = fmaxf(h[b] + fc1_b[j], 0.0f) * w2j;

    int lane = j & 63, wid = j >> 6;
#pragma unroll
    for (int b = 0; b < NB; b++)
#pragma unroll
        for (int off = 32; off > 0; off >>= 1)
            contrib[b] += __shfl_down(contrib[b], off, 64);

    __shared__ float sred[4][NB];
    if (lane == 0) {
#pragma unroll
        for (int b = 0; b < NB; b++) sred[wid][b] = contrib[b];
    }
    __syncthreads();
    if (j < NB) {
        float t = sred[0][j] + sred[1][j] + sred[2][j] + sred[3][j] + fc2_b[0];
        prob[j] = 100.0f / (1.0f + expf(-t));
    }
}

// ---------------------------------------------------------------------------
// points: zero the field, then exact top-10 of noise (free cells) per batch.
// ---------------------------------------------------------------------------
__global__ __launch_bounds__(256) void zero_pts_kernel(float4* __restrict__ out)
{
    out[blockIdx.x * 256 + threadIdx.x] = make_float4(0.f, 0.f, 0.f, 0.f);
}

#define BPB 32   // blocks per batch in stage 1

__global__ __launch_bounds__(256) void topk1_kernel(
    const float* __restrict__ bnd, const float* __restrict__ noise,
    U64* __restrict__ cand)
{
    int blk = blockIdx.x;
    int b   = blockIdx.y;
    int tid = threadIdx.x;
    int vbase = blk * (GV / BPB);
    const float* bd = bnd + (size_t)b * GV + vbase;
    const float* nz = noise + (size_t)b * GV + vbase;

    U64 top[10];
#pragma unroll
    for (int k = 0; k < 10; k++) top[k] = 0ull;

    for (int i = 0; i < (GV / BPB) / 256; i++) {
        int e = i * 256 + tid;
        float bv = bd[e];
        float s  = nz[e];
        U64 p = (bv > 0.5f) ? 0ull
              : ((((U64)__float_as_uint(s)) << 32) | (unsigned)(vbase + e));
        if (p > top[9]) {
#pragma unroll
            for (int k = 0; k < 10; k++) {
                U64 mx = p > top[k] ? p : top[k];
                U64 mn = p > top[k] ? top[k] : p;
                top[k] = mx; p = mn;
            }
        }
    }

    __shared__ U64 lcand[256 * 10];
    __shared__ U64 rv[256];
    __shared__ int rp[256];
#pragma unroll
    for (int k = 0; k < 10; k++) lcand[tid * 10 + k] = top[k];
    __syncthreads();

    for (int pass = 0; pass < 10; pass++) {
        U64 bv = 0; int bp = 0;
        for (int i = tid; i < 2560; i += 256) {
            U64 xv = lcand[i];
            if (xv > bv) { bv = xv; bp = i; }
        }
        rv[tid] = bv; rp[tid] = bp;
        __syncthreads();
        for (int off = 128; off > 0; off >>= 1) {
            if (tid < off) {
                if (rv[tid + off] > rv[tid]) { rv[tid] = rv[tid + off]; rp[tid] = rp[tid + off]; }
            }
            __syncthreads();
        }
        if (tid == 0) {
            cand[((size_t)b * BPB + blk) * 10 + pass] = rv[0];
            lcand[rp[0]] = 0ull;
        }
        __syncthreads();
    }
}

__global__ __launch_bounds__(256) void topk2_kernel(
    const U64* __restrict__ cand, float* __restrict__ pts)
{
    int b = blockIdx.x, tid = threadIdx.x;
    __shared__ U64 lc[BPB * 10];
    __shared__ U64 rv[256];
    __shared__ int rp[256];
    __shared__ int widx[10];
    for (int i = tid; i < BPB * 10; i += 256) lc[i] = cand[(size_t)b * BPB * 10 + i];
    __syncthreads();

    for (int pass = 0; pass < 10; pass++) {
        U64 bv = 0; int bp = 0;
        for (int i = tid; i < BPB * 10; i += 256) {
            U64 xv = lc[i];
            if (xv > bv) { bv = xv; bp = i; }
        }
        rv[tid] = bv; rp[tid] = bp;
        __syncthreads();
        for (int off = 128; off > 0; off >>= 1) {
            if (tid < off) {
                if (rv[tid + off] > rv[tid]) { rv[tid] = rv[tid + off]; rp[tid] = rp[tid + off]; }
            }
            __syncthreads();
        }
        if (tid == 0) { widx[pass] = (int)(rv[0] & 0xffffffffu); lc[rp[0]] = 0ull; }
        __syncthreads();
    }
    if (tid < 10) pts[(size_t)b * GV + widx[tid]] = 1.0f;
}

// ---------------------------------------------------------------------------
extern "C" void kernel_launch(void* const* d_in, const int* in_sizes, int n_in,
                              void* d_out, int out_size, void* d_ws, size_t ws_size,
                              hipStream_t stream)
{
    const float* bnd   = (const float*)d_in[0];
    const float* w1    = (const float*)d_in[1];
    const float* b1    = (const float*)d_in[2];
    const float* w2    = (const float*)d_in[3];
    const float* b2    = (const float*)d_in[4];
    const float* fw1   = (const float*)d_in[5];
    const float* fb1   = (const float*)d_in[6];
    const float* fw2   = (const float*)d_in[7];
    const float* fb2   = (const float*)d_in[8];
    const float* noise = (const float*)d_in[9];

    float* out = (float*)d_out;
    char* ws = (char*)d_ws;

    const size_t xbuf_off = 0;                       // 8*GV*4      = 8 MB
    const size_t pacc_off = xbuf_off + (size_t)NB * GV * 4;   // 512 KB
    const size_t cand_off = pacc_off + (size_t)NB * 64 * 256 * 4;
    const size_t zbuf_off = cand_off + (size_t)NB * BPB * 10 * 8;
    const size_t zb_bytes = (size_t)27 * GV * 2;     // 13.5 MB per batch

    float* xbuf = (float*)(ws + xbuf_off);
    float* pacc = (float*)(ws + pacc_off);
    U64*   cand = (U64*)(ws + cand_off);
    u16*   zbuf = (u16*)(ws + zbuf_off);

    bool batched = (ws_size >= zbuf_off + (size_t)NB * zb_bytes);

    if (batched) {
        dim3 gA(GV / 256, NB);
        convA_kernel<<<gA, 256, 0, stream>>>(bnd, (size_t)GV, zbuf, (size_t)27 * GV,
                                             w1, b1, w2);
        convB_kernel<<<gA, 256, 0, stream>>>(zbuf, (size_t)27 * GV, xbuf, (size_t)GV, b2);
    } else {
        for (int b = 0; b < NB; b++) {
            convA_kernel<<<GV / 256, 256, 0, stream>>>(bnd + (size_t)b * GV, 0,
                                                       zbuf, 0, w1, b1, w2);
            convB_kernel<<<GV / 256, 256, 0, stream>>>(zbuf, 0,
                                                       xbuf + (size_t)b * GV, 0, b2);
        }
    }

    dim3 gfc(64, 64);
    fc1_kernel<<<gfc, 256, 0, stream>>>(fw1, xbuf, pacc);
    fc_final_kernel<<<1, 256, 0, stream>>>(pacc, fb1, fw2, fb2, out + (size_t)NB * GV);

    zero_pts_kernel<<<(NB * GV / 4) / 256, 256, 0, stream>>>((float4*)out);
    dim3 gt(BPB, NB);
    topk1_kernel<<<gt, 256, 0, stream>>>(bnd, noise, cand);
    topk2_kernel<<<NB, 256, 0, stream>>>(cand, out);
}

// Round 4
// 256.437 us; speedup vs baseline: 2.0517x; 1.4109x over previous
//
#include <hip/hip_runtime.h>
#include <math.h>

#define G 64
#define GV (G*G*G)      // 262144
#define NB 8

typedef unsigned short u16;
typedef unsigned int u32;
typedef unsigned long long U64;
typedef __bf16 bf16x8 __attribute__((ext_vector_type(8)));
typedef float f32x4 __attribute__((ext_vector_type(4)));

union BF8 { u16 s[8]; bf16x8 v; };

__device__ __forceinline__ float bf2f(u16 h) {
    union { u32 u; float f; } c; c.u = ((u32)h) << 16; return c.f;
}
__device__ __forceinline__ u16 f2bf(float f) {
    union { float f; u32 u; } c; c.f = f;
    u32 u = c.u;
    return (u16)((u + 0x7fffu + ((u >> 16) & 1u)) >> 16);   // RNE
}
__device__ __forceinline__ u32 cvt_pk_bf16(float lo, float hi) {
    u32 r;
    asm volatile("v_cvt_pk_bf16_f32 %0, %1, %2" : "=v"(r) : "v"(lo), "v"(hi));
    return r;
}

#define YSTRIDE 76   // u32 per voxel row: yh at [0..35], yl at [40..75] (16B-aligned)

// ---------------------------------------------------------------------------
// convA via MFMA, split-precision (hi/lo bf16 = ~f32 accuracy everywhere
// except the final z->bf16 store, matching the R2-passing error level):
//   GEMM1: Y^T[64c x 16v] = (W1h+W1l)[64c x 32k] @ X^T[32k x 16v]  (+bias C)
//   relu -> (yh, yl) bf16 pair -> per-wave LDS tile [16v][76 u32]
//   GEMM2: Z^T[32t x 16v] = W2h@Yh + W2h@Yl + W2l@Yh
// All MFMA = 16x16x32 bf16. Block: 256 thr = 4 waves, box 4z x 4y x 64x.
// ---------------------------------------------------------------------------
__global__ __launch_bounds__(256) void convA_mfma_kernel(
    const float* __restrict__ bnd,
    const float* __restrict__ w1, const float* __restrict__ b1,
    const float* __restrict__ w2,
    u16* __restrict__ zbuf)
{
    int b = blockIdx.y;
    const float* bd = bnd + (size_t)b * GV;
    u16* zb = zbuf + (size_t)b * (27 * (size_t)GV);

    __shared__ __align__(16) u16 halo[2378];              // 6*6*66 + zero slot
    __shared__ __align__(16) u32 Ylds[4][16 * YSTRIDE];   // per-wave Y tile

    int tid = threadIdx.x;
    int z0 = (blockIdx.x >> 4) * 4, y0 = (blockIdx.x & 15) * 4;

    // ---- halo fill (bf16 bit patterns 0x3F80 / 0) ----
    for (int i = tid; i < 2378; i += 256) {
        u16 hval = 0;
        if (i < 2376) {
            int hz = i / 396, rem = i - hz * 396;
            int hy = rem / 66, hx = rem - hy * 66;
            int gz = z0 + hz - 1, gy = y0 + hy - 1, gx = hx - 1;
            if (((unsigned)gz < (unsigned)G) & ((unsigned)gy < (unsigned)G) &
                ((unsigned)gx < (unsigned)G)) {
                float f = bd[(gz << 12) + (gy << 6) + gx];
                hval = (f > 0.5f) ? (u16)0x3F80 : (u16)0;
            }
        }
        halo[i] = hval;
    }

    int wv = tid >> 6, lane = tid & 63;
    int g = lane >> 4, lr = lane & 15;

    // ---- preload weight A-fragments, hi/lo split ----
    // A layout: row = lane&15, k = 8*(lane>>4)+j
    BF8 w1Ah[4], w1Al[4];           // GEMM1 A: 4 c-tiles, K=27 pad 32
#pragma unroll
    for (int m = 0; m < 4; m++) {
        int c = 16 * m + lr;
#pragma unroll
        for (int j = 0; j < 8; j++) {
            int kk = 8 * g + j;
            float w = (kk < 27) ? w1[c * 27 + kk] : 0.0f;
            u16 hi = f2bf(w);
            w1Ah[m].s[j] = hi;
            w1Al[m].s[j] = f2bf(w - bf2f(hi));
        }
    }
    BF8 w2Ah[2][2], w2Al[2][2];     // GEMM2 A: 2 t-tiles x 2 K-steps
#pragma unroll
    for (int m2 = 0; m2 < 2; m2++) {
        int t = 16 * m2 + lr;
#pragma unroll
        for (int ks = 0; ks < 2; ks++)
#pragma unroll
            for (int j = 0; j < 8; j++) {
                int ch = 32 * ks + 8 * g + j;
                float w = (t < 27) ? w2[ch * 27 + t] : 0.0f;
                u16 hi = f2bf(w);
                w2Ah[m2][ks].s[j] = hi;
                w2Al[m2][ks].s[j] = f2bf(w - bf2f(hi));
            }
    }
    float bias[4][4];               // b1 for D rows c = 16m+4g+r (exact f32)
#pragma unroll
    for (int m = 0; m < 4; m++)
#pragma unroll
        for (int r = 0; r < 4; r++) bias[m][r] = b1[16 * m + 4 * g + r];

    // ---- per-lane tap offsets for the X^T gather ----
    int tapoff[8]; bool tapok[8];
#pragma unroll
    for (int j = 0; j < 8; j++) {
        int kk = 8 * g + j;
        int kc = kk < 27 ? kk : 0;
        int dz = kc / 9, ry = kc - dz * 9;
        int dy = ry / 3, dx = ry - dy * 3;
        tapoff[j] = dz * 396 + dy * 66 + dx;
        tapok[j] = (kk < 27);
    }

    __syncthreads();

    u32* myY = &Ylds[wv][0];

    for (int li = 0; li < 4; li++) {
        int l = wv * 4 + li;
        int zl = l >> 2, yl = l & 3;
        int lineoff = (zl * 6 + yl) * 66 + lr;
        int vbase = ((z0 + zl) << 12) + ((y0 + yl) << 6);

        for (int xt = 0; xt < 4; xt++) {
            int x0 = xt * 16;

            // gather X^T B-frag: col=v=lr, k=8g+j
            BF8 xB;
#pragma unroll
            for (int j = 0; j < 8; j++) {
                int a = lineoff + x0 + tapoff[j];
                a = tapok[j] ? a : 2376;      // zero slot
                xB.s[j] = halo[a];
            }

            // GEMM1: Y^T = (W1l + W1h) @ X^T  (+bias via C)
            f32x4 yac[4];
#pragma unroll
            for (int m = 0; m < 4; m++) {
                f32x4 c0;
                c0[0] = bias[m][0]; c0[1] = bias[m][1];
                c0[2] = bias[m][2]; c0[3] = bias[m][3];
                c0 = __builtin_amdgcn_mfma_f32_16x16x32_bf16(
                    w1Al[m].v, xB.v, c0, 0, 0, 0);
                yac[m] = __builtin_amdgcn_mfma_f32_16x16x32_bf16(
                    w1Ah[m].v, xB.v, c0, 0, 0, 0);
            }

            // relu + split hi/lo bf16 pairs (c,c+1) -> Y_lds[v][ch]
#pragma unroll
            for (int m = 0; m < 4; m++) {
                float a0 = fmaxf(yac[m][0], 0.f), a1 = fmaxf(yac[m][1], 0.f);
                float a2 = fmaxf(yac[m][2], 0.f), a3 = fmaxf(yac[m][3], 0.f);
                u32 h01 = cvt_pk_bf16(a0, a1);
                u32 h23 = cvt_pk_bf16(a2, a3);
                u32 l01 = cvt_pk_bf16(a0 - bf2f((u16)(h01 & 0xffffu)),
                                      a1 - bf2f((u16)(h01 >> 16)));
                u32 l23 = cvt_pk_bf16(a2 - bf2f((u16)(h23 & 0xffffu)),
                                      a3 - bf2f((u16)(h23 >> 16)));
                int c0u = (16 * m + 4 * g) >> 1;       // u32 index within row
                myY[lr * YSTRIDE + c0u]          = h01;
                myY[lr * YSTRIDE + c0u + 1]      = h23;
                myY[lr * YSTRIDE + 40 + c0u]     = l01;
                myY[lr * YSTRIDE + 40 + c0u + 1] = l23;
            }
            asm volatile("" ::: "memory");   // order LDS write->read

            // GEMM2: Z^T = W2h@Yh + W2h@Yl + W2l@Yh
            f32x4 zac[2];
            zac[0] = f32x4{0.f, 0.f, 0.f, 0.f};
            zac[1] = f32x4{0.f, 0.f, 0.f, 0.f};
#pragma unroll
            for (int ks = 0; ks < 2; ks++) {
                // B-frag k(ch) = 32ks+8g+j  ->  u32 offset 16ks+4g (bug fix)
                bf16x8 yBh = *(const bf16x8*)&myY[lr * YSTRIDE + 16 * ks + 4 * g];
                bf16x8 yBl = *(const bf16x8*)&myY[lr * YSTRIDE + 40 + 16 * ks + 4 * g];
#pragma unroll
                for (int m2 = 0; m2 < 2; m2++) {
                    zac[m2] = __builtin_amdgcn_mfma_f32_16x16x32_bf16(
                        w2Al[m2][ks].v, yBh, zac[m2], 0, 0, 0);
                    zac[m2] = __builtin_amdgcn_mfma_f32_16x16x32_bf16(
                        w2Ah[m2][ks].v, yBl, zac[m2], 0, 0, 0);
                    zac[m2] = __builtin_amdgcn_mfma_f32_16x16x32_bf16(
                        w2Ah[m2][ks].v, yBh, zac[m2], 0, 0, 0);
                }
            }

            // store Z rows t<27, voxel = vbase + x0 + lr
            int vg = vbase + x0 + lr;
#pragma unroll
            for (int m2 = 0; m2 < 2; m2++)
#pragma unroll
                for (int r = 0; r < 4; r++) {
                    int t = 16 * m2 + 4 * g + r;
                    if (t < 27)
                        zb[(size_t)t * GV + vg] = f2bf(zac[m2][r]);
                }
        }
    }
}

// ---------------------------------------------------------------------------
// Kernel B: conv2 tap-stencil: x2(v) = relu(b2 + sum_t z_t(v + d_t))
// ---------------------------------------------------------------------------
__global__ __launch_bounds__(256) void convB_kernel(
    const u16* __restrict__ zbuf, size_t z_bs,
    float* __restrict__ xout, size_t x_bs,
    const float* __restrict__ b2)
{
    int b = blockIdx.y;
    const u16* zb = zbuf + (size_t)b * z_bs;
    float* xo = xout + (size_t)b * x_bs;

    int v  = blockIdx.x * 256 + threadIdx.x;
    int zc = v >> 12, yc = (v >> 6) & 63, xc = v & 63;
    float acc = b2[0];
#pragma unroll
    for (int dz = -1; dz <= 1; dz++)
#pragma unroll
    for (int dy = -1; dy <= 1; dy++)
#pragma unroll
    for (int dx = -1; dx <= 1; dx++) {
        int t = (dz + 1) * 9 + (dy + 1) * 3 + (dx + 1);
        int zz = zc + dz, yy = yc + dy, xx = xc + dx;
        bool ok = ((unsigned)zz < (unsigned)G) & ((unsigned)yy < (unsigned)G) &
                  ((unsigned)xx < (unsigned)G);
        if (ok) acc += bf2f(zb[(size_t)t * GV + (zz << 12) + (yy << 6) + xx]);
    }
    xo[v] = fmaxf(acc, 0.0f);
}

// ---------------------------------------------------------------------------
// fc1: block (jt, vc) handles 4 rows j0..j0+3 x 4096-v chunk, all 8 batches.
// ---------------------------------------------------------------------------
__global__ __launch_bounds__(256) void fc1_kernel(
    const float* __restrict__ W, const float* __restrict__ x,
    float* __restrict__ pacc)
{
    int jt = blockIdx.x;            // 0..63
    int vc = blockIdx.y;            // 0..63
    int tid = threadIdx.x;
    int j0 = jt * 4;
    size_t v0 = (size_t)vc * 4096;

    const float4* Wp[4];
#pragma unroll
    for (int jj = 0; jj < 4; jj++)
        Wp[jj] = reinterpret_cast<const float4*>(W + (size_t)(j0 + jj) * GV + v0);
    const float4* Xp[NB];
#pragma unroll
    for (int b = 0; b < NB; b++)
        Xp[b] = reinterpret_cast<const float4*>(x + (size_t)b * GV + v0);

    float acc[4][NB];
#pragma unroll
    for (int jj = 0; jj < 4; jj++)
#pragma unroll
        for (int b = 0; b < NB; b++) acc[jj][b] = 0.0f;

    for (int i = 0; i < 4; i++) {
        int e = i * 256 + tid;
        float4 wvv[4];
#pragma unroll
        for (int jj = 0; jj < 4; jj++) wvv[jj] = Wp[jj][e];
#pragma unroll
        for (int b = 0; b < NB; b++) {
            float4 xv = Xp[b][e];
#pragma unroll
            for (int jj = 0; jj < 4; jj++) {
                acc[jj][b] = fmaf(wvv[jj].x, xv.x, acc[jj][b]);
                acc[jj][b] = fmaf(wvv[jj].y, xv.y, acc[jj][b]);
                acc[jj][b] = fmaf(wvv[jj].z, xv.z, acc[jj][b]);
                acc[jj][b] = fmaf(wvv[jj].w, xv.w, acc[jj][b]);
            }
        }
    }

    __shared__ float sacc[256][36];
    float4* row = reinterpret_cast<float4*>(&sacc[tid][0]);
#pragma unroll
    for (int jj = 0; jj < 4; jj++) {
        row[jj * 2 + 0] = make_float4(acc[jj][0], acc[jj][1], acc[jj][2], acc[jj][3]);
        row[jj * 2 + 1] = make_float4(acc[jj][4], acc[jj][5], acc[jj][6], acc[jj][7]);
    }
    __syncthreads();

    __shared__ float p2[8][40];
    {
        int o = tid & 31, gg = tid >> 5;
        float s = 0.0f;
#pragma unroll
        for (int k = 0; k < 32; k++) s += sacc[gg * 32 + k][o];
        p2[gg][o] = s;
    }
    __syncthreads();
    if (tid < 32) {
        float s = 0.0f;
#pragma unroll
        for (int gg = 0; gg < 8; gg++) s += p2[gg][tid];
        int jj = tid >> 3, b = tid & 7;
        pacc[((size_t)b * 64 + vc) * 256 + (j0 + jj)] = s;
    }
}

// ---------------------------------------------------------------------------
__global__ __launch_bounds__(256) void fc_final_kernel(
    const float* __restrict__ pacc, const float* __restrict__ fc1_b,
    const float* __restrict__ fc2_w, const float* __restrict__ fc2_b,
    float* __restrict__ prob)
{
    int j = threadIdx.x;
    float h[NB];
#pragma unroll
    for (int b = 0; b < NB; b++) h[b] = 0.0f;
    for (int c = 0; c < 64; c++) {
#pragma unroll
        for (int b = 0; b < NB; b++)
            h[b] += pacc[((size_t)b * 64 + c) * 256 + j];
    }
    float w2j = fc2_w[j];
    float contrib[NB];
#pragma unroll
    for (int b = 0; b < NB; b++)
        contrib[b] = fmaxf(h[b] + fc1_b[j], 0.0f) * w2j;

    int lane = j & 63, wid = j >> 6;
#pragma unroll
    for (int b = 0; b < NB; b++)
#pragma unroll
        for (int off = 32; off > 0; off >>= 1)
            contrib[b] += __shfl_down(contrib[b], off, 64);

    __shared__ float sred[4][NB];
    if (lane == 0) {
#pragma unroll
        for (int b = 0; b < NB; b++) sred[wid][b] = contrib[b];
    }
    __syncthreads();
    if (j < NB) {
        float t = sred[0][j] + sred[1][j] + sred[2][j] + sred[3][j] + fc2_b[0];
        prob[j] = 100.0f / (1.0f + expf(-t));
    }
}

// ---------------------------------------------------------------------------
__global__ __launch_bounds__(256) void zero_pts_kernel(float4* __restrict__ out)
{
    out[blockIdx.x * 256 + threadIdx.x] = make_float4(0.f, 0.f, 0.f, 0.f);
}

#define BPB 32

__global__ __launch_bounds__(256) void topk1_kernel(
    const float* __restrict__ bnd, const float* __restrict__ noise,
    U64* __restrict__ cand)
{
    int blk = blockIdx.x;
    int b   = blockIdx.y;
    int tid = threadIdx.x;
    int vbase = blk * (GV / BPB);
    const float* bd = bnd + (size_t)b * GV + vbase;
    const float* nz = noise + (size_t)b * GV + vbase;

    U64 top[10];
#pragma unroll
    for (int k = 0; k < 10; k++) top[k] = 0ull;

    for (int i = 0; i < (GV / BPB) / 256; i++) {
        int e = i * 256 + tid;
        float bv = bd[e];
        float s  = nz[e];
        U64 p = (bv > 0.5f) ? 0ull
              : ((((U64)__float_as_uint(s)) << 32) | (unsigned)(vbase + e));
        if (p > top[9]) {
#pragma unroll
            for (int k = 0; k < 10; k++) {
                U64 mx = p > top[k] ? p : top[k];
                U64 mn = p > top[k] ? top[k] : p;
                top[k] = mx; p = mn;
            }
        }
    }

    __shared__ U64 lcand[256 * 10];
    __shared__ U64 rv[256];
    __shared__ int rp[256];
#pragma unroll
    for (int k = 0; k < 10; k++) lcand[tid * 10 + k] = top[k];
    __syncthreads();

    for (int pass = 0; pass < 10; pass++) {
        U64 bv = 0; int bp = 0;
        for (int i = tid; i < 2560; i += 256) {
            U64 xv = lcand[i];
            if (xv > bv) { bv = xv; bp = i; }
        }
        rv[tid] = bv; rp[tid] = bp;
        __syncthreads();
        for (int off = 128; off > 0; off >>= 1) {
            if (tid < off) {
                if (rv[tid + off] > rv[tid]) { rv[tid] = rv[tid + off]; rp[tid] = rp[tid + off]; }
            }
            __syncthreads();
        }
        if (tid == 0) {
            cand[((size_t)b * BPB + blk) * 10 + pass] = rv[0];
            lcand[rp[0]] = 0ull;
        }
        __syncthreads();
    }
}

__global__ __launch_bounds__(256) void topk2_kernel(
    const U64* __restrict__ cand, float* __restrict__ pts)
{
    int b = blockIdx.x, tid = threadIdx.x;
    __shared__ U64 lc[BPB * 10];
    __shared__ U64 rv[256];
    __shared__ int rp[256];
    __shared__ int widx[10];
    for (int i = tid; i < BPB * 10; i += 256) lc[i] = cand[(size_t)b * BPB * 10 + i];
    __syncthreads();

    for (int pass = 0; pass < 10; pass++) {
        U64 bv = 0; int bp = 0;
        for (int i = tid; i < BPB * 10; i += 256) {
            U64 xv = lc[i];
            if (xv > bv) { bv = xv; bp = i; }
        }
        rv[tid] = bv; rp[tid] = bp;
        __syncthreads();
        for (int off = 128; off > 0; off >>= 1) {
            if (tid < off) {
                if (rv[tid + off] > rv[tid]) { rv[tid] = rv[tid + off]; rp[tid] = rp[tid + off]; }
            }
            __syncthreads();
        }
        if (tid == 0) { widx[pass] = (int)(rv[0] & 0xffffffffu); lc[rp[0]] = 0ull; }
        __syncthreads();
    }
    if (tid < 10) pts[(size_t)b * GV + widx[tid]] = 1.0f;
}

// ---------------------------------------------------------------------------
extern "C" void kernel_launch(void* const* d_in, const int* in_sizes, int n_in,
                              void* d_out, int out_size, void* d_ws, size_t ws_size,
                              hipStream_t stream)
{
    const float* bnd   = (const float*)d_in[0];
    const float* w1    = (const float*)d_in[1];
    const float* b1    = (const float*)d_in[2];
    const float* w2    = (const float*)d_in[3];
    const float* b2    = (const float*)d_in[4];
    const float* fw1   = (const float*)d_in[5];
    const float* fb1   = (const float*)d_in[6];
    const float* fw2   = (const float*)d_in[7];
    const float* fb2   = (const float*)d_in[8];
    const float* noise = (const float*)d_in[9];

    float* out = (float*)d_out;
    char* ws = (char*)d_ws;

    const size_t xbuf_off = 0;                                 // 8 MB
    const size_t pacc_off = xbuf_off + (size_t)NB * GV * 4;    // 512 KB
    const size_t cand_off = pacc_off + (size_t)NB * 64 * 256 * 4;
    const size_t zbuf_off = cand_off + (size_t)NB * BPB * 10 * 8;

    float* xbuf = (float*)(ws + xbuf_off);
    float* pacc = (float*)(ws + pacc_off);
    U64*   cand = (U64*)(ws + cand_off);
    u16*   zbuf = (u16*)(ws + zbuf_off);                       // 8 x 13.5 MB

    dim3 gA(256, NB);       // (4z x 4y) boxes x 8 batches
    convA_mfma_kernel<<<gA, 256, 0, stream>>>(bnd, w1, b1, w2, zbuf);

    dim3 gB(GV / 256, NB);
    convB_kernel<<<gB, 256, 0, stream>>>(zbuf, (size_t)27 * GV, xbuf, (size_t)GV, b2);

    dim3 gfc(64, 64);
    fc1_kernel<<<gfc, 256, 0, stream>>>(fw1, xbuf, pacc);
    fc_final_kernel<<<1, 256, 0, stream>>>(pacc, fb1, fw2, fb2, out + (size_t)NB * GV);

    zero_pts_kernel<<<(NB * GV / 4) / 256, 256, 0, stream>>>((float4*)out);
    dim3 gt(BPB, NB);
    topk1_kernel<<<gt, 256, 0, stream>>>(bnd, noise, cand);
    topk2_kernel<<<NB, 256, 0, stream>>>(cand, out);
}

// Round 5
// 254.086 us; speedup vs baseline: 2.0707x; 1.0093x over previous
//
#include <hip/hip_runtime.h>
#include <math.h>

#define G 64
#define GV (G*G*G)      // 262144
#define NB 8

typedef unsigned short u16;
typedef unsigned int u32;
typedef unsigned long long U64;
typedef __bf16 bf16x8 __attribute__((ext_vector_type(8)));
typedef float f32x4 __attribute__((ext_vector_type(4)));

union BF8 { u16 s[8]; bf16x8 v; };

__device__ __forceinline__ float bf2f(u16 h) {
    union { u32 u; float f; } c; c.u = ((u32)h) << 16; return c.f;
}
__device__ __forceinline__ u16 f2bf(float f) {
    union { float f; u32 u; } c; c.f = f;
    u32 u = c.u;
    return (u16)((u + 0x7fffu + ((u >> 16) & 1u)) >> 16);   // RNE
}
__device__ __forceinline__ u32 cvt_pk_bf16(float lo, float hi) {
    u32 r;
    asm volatile("v_cvt_pk_bf16_f32 %0, %1, %2" : "=v"(r) : "v"(lo), "v"(hi));
    return r;
}

#define YSTRIDE 76   // u32 per voxel row: yh at [0..35], yl at [40..75] (16B-aligned)

// ---------------------------------------------------------------------------
// convA via MFMA, split-precision (hi/lo bf16 = ~f32 accuracy everywhere
// except the final z->bf16 store, matching the R2-passing error level):
//   GEMM1: Y^T[64c x 16v] = (W1h+W1l)[64c x 32k] @ X^T[32k x 16v]  (+bias C)
//   relu -> (yh, yl) bf16 pair -> per-wave LDS tile [16v][76 u32]
//   GEMM2: Z^T[32t x 16v] = W2h@Yh + W2h@Yl + W2l@Yh
// All MFMA = 16x16x32 bf16. Block: 256 thr = 4 waves, box 4z x 4y x 64x.
// ---------------------------------------------------------------------------
__global__ __launch_bounds__(256) void convA_mfma_kernel(
    const float* __restrict__ bnd,
    const float* __restrict__ w1, const float* __restrict__ b1,
    const float* __restrict__ w2,
    u16* __restrict__ zbuf)
{
    int b = blockIdx.y;
    const float* bd = bnd + (size_t)b * GV;
    u16* zb = zbuf + (size_t)b * (27 * (size_t)GV);

    __shared__ __align__(16) u16 halo[2378];              // 6*6*66 + zero slot
    __shared__ __align__(16) u32 Ylds[4][16 * YSTRIDE];   // per-wave Y tile

    int tid = threadIdx.x;
    int z0 = (blockIdx.x >> 4) * 4, y0 = (blockIdx.x & 15) * 4;

    // ---- halo fill (bf16 bit patterns 0x3F80 / 0) ----
    for (int i = tid; i < 2378; i += 256) {
        u16 hval = 0;
        if (i < 2376) {
            int hz = i / 396, rem = i - hz * 396;
            int hy = rem / 66, hx = rem - hy * 66;
            int gz = z0 + hz - 1, gy = y0 + hy - 1, gx = hx - 1;
            if (((unsigned)gz < (unsigned)G) & ((unsigned)gy < (unsigned)G) &
                ((unsigned)gx < (unsigned)G)) {
                float f = bd[(gz << 12) + (gy << 6) + gx];
                hval = (f > 0.5f) ? (u16)0x3F80 : (u16)0;
            }
        }
        halo[i] = hval;
    }

    int wv = tid >> 6, lane = tid & 63;
    int g = lane >> 4, lr = lane & 15;

    // ---- preload weight A-fragments, hi/lo split ----
    BF8 w1Ah[4], w1Al[4];           // GEMM1 A: 4 c-tiles, K=27 pad 32
#pragma unroll
    for (int m = 0; m < 4; m++) {
        int c = 16 * m + lr;
#pragma unroll
        for (int j = 0; j < 8; j++) {
            int kk = 8 * g + j;
            float w = (kk < 27) ? w1[c * 27 + kk] : 0.0f;
            u16 hi = f2bf(w);
            w1Ah[m].s[j] = hi;
            w1Al[m].s[j] = f2bf(w - bf2f(hi));
        }
    }
    BF8 w2Ah[2][2], w2Al[2][2];     // GEMM2 A: 2 t-tiles x 2 K-steps
#pragma unroll
    for (int m2 = 0; m2 < 2; m2++) {
        int t = 16 * m2 + lr;
#pragma unroll
        for (int ks = 0; ks < 2; ks++)
#pragma unroll
            for (int j = 0; j < 8; j++) {
                int ch = 32 * ks + 8 * g + j;
                float w = (t < 27) ? w2[ch * 27 + t] : 0.0f;
                u16 hi = f2bf(w);
                w2Ah[m2][ks].s[j] = hi;
                w2Al[m2][ks].s[j] = f2bf(w - bf2f(hi));
            }
    }
    float bias[4][4];               // b1 for D rows c = 16m+4g+r (exact f32)
#pragma unroll
    for (int m = 0; m < 4; m++)
#pragma unroll
        for (int r = 0; r < 4; r++) bias[m][r] = b1[16 * m + 4 * g + r];

    // ---- per-lane tap offsets for the X^T gather ----
    int tapoff[8]; bool tapok[8];
#pragma unroll
    for (int j = 0; j < 8; j++) {
        int kk = 8 * g + j;
        int kc = kk < 27 ? kk : 0;
        int dz = kc / 9, ry = kc - dz * 9;
        int dy = ry / 3, dx = ry - dy * 3;
        tapoff[j] = dz * 396 + dy * 66 + dx;
        tapok[j] = (kk < 27);
    }

    __syncthreads();

    u32* myY = &Ylds[wv][0];

    for (int li = 0; li < 4; li++) {
        int l = wv * 4 + li;
        int zl = l >> 2, yl = l & 3;
        int lineoff = (zl * 6 + yl) * 66 + lr;
        int vbase = ((z0 + zl) << 12) + ((y0 + yl) << 6);

        for (int xt = 0; xt < 4; xt++) {
            int x0 = xt * 16;

            // gather X^T B-frag: col=v=lr, k=8g+j
            BF8 xB;
#pragma unroll
            for (int j = 0; j < 8; j++) {
                int a = lineoff + x0 + tapoff[j];
                a = tapok[j] ? a : 2376;      // zero slot
                xB.s[j] = halo[a];
            }

            // GEMM1: Y^T = (W1l + W1h) @ X^T  (+bias via C)
            f32x4 yac[4];
#pragma unroll
            for (int m = 0; m < 4; m++) {
                f32x4 c0;
                c0[0] = bias[m][0]; c0[1] = bias[m][1];
                c0[2] = bias[m][2]; c0[3] = bias[m][3];
                c0 = __builtin_amdgcn_mfma_f32_16x16x32_bf16(
                    w1Al[m].v, xB.v, c0, 0, 0, 0);
                yac[m] = __builtin_amdgcn_mfma_f32_16x16x32_bf16(
                    w1Ah[m].v, xB.v, c0, 0, 0, 0);
            }

            // relu + split hi/lo bf16 pairs (c,c+1) -> Y_lds[v][ch]
#pragma unroll
            for (int m = 0; m < 4; m++) {
                float a0 = fmaxf(yac[m][0], 0.f), a1 = fmaxf(yac[m][1], 0.f);
                float a2 = fmaxf(yac[m][2], 0.f), a3 = fmaxf(yac[m][3], 0.f);
                u32 h01 = cvt_pk_bf16(a0, a1);
                u32 h23 = cvt_pk_bf16(a2, a3);
                u32 l01 = cvt_pk_bf16(a0 - bf2f((u16)(h01 & 0xffffu)),
                                      a1 - bf2f((u16)(h01 >> 16)));
                u32 l23 = cvt_pk_bf16(a2 - bf2f((u16)(h23 & 0xffffu)),
                                      a3 - bf2f((u16)(h23 >> 16)));
                int c0u = (16 * m + 4 * g) >> 1;       // u32 index within row
                myY[lr * YSTRIDE + c0u]          = h01;
                myY[lr * YSTRIDE + c0u + 1]      = h23;
                myY[lr * YSTRIDE + 40 + c0u]     = l01;
                myY[lr * YSTRIDE + 40 + c0u + 1] = l23;
            }
            asm volatile("" ::: "memory");   // order LDS write->read

            // GEMM2: Z^T = W2h@Yh + W2h@Yl + W2l@Yh
            f32x4 zac[2];
            zac[0] = f32x4{0.f, 0.f, 0.f, 0.f};
            zac[1] = f32x4{0.f, 0.f, 0.f, 0.f};
#pragma unroll
            for (int ks = 0; ks < 2; ks++) {
                bf16x8 yBh = *(const bf16x8*)&myY[lr * YSTRIDE + 16 * ks + 4 * g];
                bf16x8 yBl = *(const bf16x8*)&myY[lr * YSTRIDE + 40 + 16 * ks + 4 * g];
#pragma unroll
                for (int m2 = 0; m2 < 2; m2++) {
                    zac[m2] = __builtin_amdgcn_mfma_f32_16x16x32_bf16(
                        w2Al[m2][ks].v, yBh, zac[m2], 0, 0, 0);
                    zac[m2] = __builtin_amdgcn_mfma_f32_16x16x32_bf16(
                        w2Ah[m2][ks].v, yBl, zac[m2], 0, 0, 0);
                    zac[m2] = __builtin_amdgcn_mfma_f32_16x16x32_bf16(
                        w2Ah[m2][ks].v, yBh, zac[m2], 0, 0, 0);
                }
            }

            // store Z rows t<27, voxel = vbase + x0 + lr
            int vg = vbase + x0 + lr;
#pragma unroll
            for (int m2 = 0; m2 < 2; m2++)
#pragma unroll
                for (int r = 0; r < 4; r++) {
                    int t = 16 * m2 + 4 * g + r;
                    if (t < 27)
                        zb[(size_t)t * GV + vg] = f2bf(zac[m2][r]);
                }
        }
    }
}

// ---------------------------------------------------------------------------
// Kernel B: conv2 tap-stencil: x2(v) = relu(b2 + sum_t z_t(v + d_t))
// ---------------------------------------------------------------------------
__global__ __launch_bounds__(256) void convB_kernel(
    const u16* __restrict__ zbuf, size_t z_bs,
    float* __restrict__ xout, size_t x_bs,
    const float* __restrict__ b2)
{
    int b = blockIdx.y;
    const u16* zb = zbuf + (size_t)b * z_bs;
    float* xo = xout + (size_t)b * x_bs;

    int v  = blockIdx.x * 256 + threadIdx.x;
    int zc = v >> 12, yc = (v >> 6) & 63, xc = v & 63;
    float acc = b2[0];
#pragma unroll
    for (int dz = -1; dz <= 1; dz++)
#pragma unroll
    for (int dy = -1; dy <= 1; dy++)
#pragma unroll
    for (int dx = -1; dx <= 1; dx++) {
        int t = (dz + 1) * 9 + (dy + 1) * 3 + (dx + 1);
        int zz = zc + dz, yy = yc + dy, xx = xc + dx;
        bool ok = ((unsigned)zz < (unsigned)G) & ((unsigned)yy < (unsigned)G) &
                  ((unsigned)xx < (unsigned)G);
        if (ok) acc += bf2f(zb[(size_t)t * GV + (zz << 12) + (yy << 6) + xx]);
    }
    xo[v] = fmaxf(acc, 0.0f);
}

// ---------------------------------------------------------------------------
// fc1: block (jt, vc) handles 8 rows j0..j0+7 x 4096-v chunk, all 8 batches.
// JT=8: halves x re-read traffic vs JT=4, 256 FMA per 16 loads.
// pacc layout: [b][vc][j]
// ---------------------------------------------------------------------------
__global__ __launch_bounds__(256) void fc1_kernel(
    const float* __restrict__ W, const float* __restrict__ x,
    float* __restrict__ pacc)
{
    int jt = blockIdx.x;            // 0..31
    int vc = blockIdx.y;            // 0..63
    int tid = threadIdx.x;
    int j0 = jt * 8;
    size_t v0 = (size_t)vc * 4096;

    const float4* Wp[8];
#pragma unroll
    for (int jj = 0; jj < 8; jj++)
        Wp[jj] = reinterpret_cast<const float4*>(W + (size_t)(j0 + jj) * GV + v0);
    const float4* Xp[NB];
#pragma unroll
    for (int b = 0; b < NB; b++)
        Xp[b] = reinterpret_cast<const float4*>(x + (size_t)b * GV + v0);

    float acc[8][NB];
#pragma unroll
    for (int jj = 0; jj < 8; jj++)
#pragma unroll
        for (int b = 0; b < NB; b++) acc[jj][b] = 0.0f;

    for (int i = 0; i < 4; i++) {
        int e = i * 256 + tid;
        float4 wvv[8];
#pragma unroll
        for (int jj = 0; jj < 8; jj++) wvv[jj] = Wp[jj][e];
        float4 xv[NB];
#pragma unroll
        for (int b = 0; b < NB; b++) xv[b] = Xp[b][e];
#pragma unroll
        for (int b = 0; b < NB; b++) {
#pragma unroll
            for (int jj = 0; jj < 8; jj++) {
                acc[jj][b] = fmaf(wvv[jj].x, xv[b].x, acc[jj][b]);
                acc[jj][b] = fmaf(wvv[jj].y, xv[b].y, acc[jj][b]);
                acc[jj][b] = fmaf(wvv[jj].z, xv[b].z, acc[jj][b]);
                acc[jj][b] = fmaf(wvv[jj].w, xv[b].w, acc[jj][b]);
            }
        }
    }

    // Epilogue: two passes of the JT=4 LDS transpose reduction.
    __shared__ float sacc[256][36];
    __shared__ float p2[8][40];
#pragma unroll
    for (int pass = 0; pass < 2; pass++) {
        if (pass > 0) __syncthreads();      // protect p2/sacc reuse
        float4* row = reinterpret_cast<float4*>(&sacc[tid][0]);
#pragma unroll
        for (int jj = 0; jj < 4; jj++) {
            int js = pass * 4 + jj;
            row[jj * 2 + 0] = make_float4(acc[js][0], acc[js][1], acc[js][2], acc[js][3]);
            row[jj * 2 + 1] = make_float4(acc[js][4], acc[js][5], acc[js][6], acc[js][7]);
        }
        __syncthreads();
        {
            int o = tid & 31, gg = tid >> 5;
            float s = 0.0f;
#pragma unroll
            for (int k = 0; k < 32; k++) s += sacc[gg * 32 + k][o];
            p2[gg][o] = s;
        }
        __syncthreads();
        if (tid < 32) {
            float s = 0.0f;
#pragma unroll
            for (int gg = 0; gg < 8; gg++) s += p2[gg][tid];
            int jj = tid >> 3, b = tid & 7;
            pacc[((size_t)b * 64 + vc) * 256 + (j0 + pass * 4 + jj)] = s;
        }
    }
}

// ---------------------------------------------------------------------------
__global__ __launch_bounds__(256) void fc_final_kernel(
    const float* __restrict__ pacc, const float* __restrict__ fc1_b,
    const float* __restrict__ fc2_w, const float* __restrict__ fc2_b,
    float* __restrict__ prob)
{
    int j = threadIdx.x;
    float h[NB];
#pragma unroll
    for (int b = 0; b < NB; b++) h[b] = 0.0f;
    for (int c = 0; c < 64; c++) {
#pragma unroll
        for (int b = 0; b < NB; b++)
            h[b] += pacc[((size_t)b * 64 + c) * 256 + j];
    }
    float w2j = fc2_w[j];
    float contrib[NB];
#pragma unroll
    for (int b = 0; b < NB; b++)
        contrib[b] = fmaxf(h[b] + fc1_b[j], 0.0f) * w2j;

    int lane = j & 63, wid = j >> 6;
#pragma unroll
    for (int b = 0; b < NB; b++)
#pragma unroll
        for (int off = 32; off > 0; off >>= 1)
            contrib[b] += __shfl_down(contrib[b], off, 64);

    __shared__ float sred[4][NB];
    if (lane == 0) {
#pragma unroll
        for (int b = 0; b < NB; b++) sred[wid][b] = contrib[b];
    }
    __syncthreads();
    if (j < NB) {
        float t = sred[0][j] + sred[1][j] + sred[2][j] + sred[3][j] + fc2_b[0];
        prob[j] = 100.0f / (1.0f + expf(-t));
    }
}

// ---------------------------------------------------------------------------
__global__ __launch_bounds__(256) void zero_pts_kernel(float4* __restrict__ out)
{
    out[blockIdx.x * 256 + threadIdx.x] = make_float4(0.f, 0.f, 0.f, 0.f);
}

#define BPB 32

__global__ __launch_bounds__(256) void topk1_kernel(
    const float* __restrict__ bnd, const float* __restrict__ noise,
    U64* __restrict__ cand)
{
    int blk = blockIdx.x;
    int b   = blockIdx.y;
    int tid = threadIdx.x;
    int vbase = blk * (GV / BPB);
    const float* bd = bnd + (size_t)b * GV + vbase;
    const float* nz = noise + (size_t)b * GV + vbase;

    U64 top[10];
#pragma unroll
    for (int k = 0; k < 10; k++) top[k] = 0ull;

    for (int i = 0; i < (GV / BPB) / 256; i++) {
        int e = i * 256 + tid;
        float bv = bd[e];
        float s  = nz[e];
        U64 p = (bv > 0.5f) ? 0ull
              : ((((U64)__float_as_uint(s)) << 32) | (unsigned)(vbase + e));
        if (p > top[9]) {
#pragma unroll
            for (int k = 0; k < 10; k++) {
                U64 mx = p > top[k] ? p : top[k];
                U64 mn = p > top[k] ? top[k] : p;
                top[k] = mx; p = mn;
            }
        }
    }

    __shared__ U64 lcand[256 * 10];
    __shared__ U64 rv[256];
    __shared__ int rp[256];
#pragma unroll
    for (int k = 0; k < 10; k++) lcand[tid * 10 + k] = top[k];
    __syncthreads();

    for (int pass = 0; pass < 10; pass++) {
        U64 bv = 0; int bp = 0;
        for (int i = tid; i < 2560; i += 256) {
            U64 xv = lcand[i];
            if (xv > bv) { bv = xv; bp = i; }
        }
        rv[tid] = bv; rp[tid] = bp;
        __syncthreads();
        for (int off = 128; off > 0; off >>= 1) {
            if (tid < off) {
                if (rv[tid + off] > rv[tid]) { rv[tid] = rv[tid + off]; rp[tid] = rp[tid + off]; }
            }
            __syncthreads();
        }
        if (tid == 0) {
            cand[((size_t)b * BPB + blk) * 10 + pass] = rv[0];
            lcand[rp[0]] = 0ull;
        }
        __syncthreads();
    }
}

__global__ __launch_bounds__(256) void topk2_kernel(
    const U64* __restrict__ cand, float* __restrict__ pts)
{
    int b = blockIdx.x, tid = threadIdx.x;
    __shared__ U64 lc[BPB * 10];
    __shared__ U64 rv[256];
    __shared__ int rp[256];
    __shared__ int widx[10];
    for (int i = tid; i < BPB * 10; i += 256) lc[i] = cand[(size_t)b * BPB * 10 + i];
    __syncthreads();

    for (int pass = 0; pass < 10; pass++) {
        U64 bv = 0; int bp = 0;
        for (int i = tid; i < BPB * 10; i += 256) {
            U64 xv = lc[i];
            if (xv > bv) { bv = xv; bp = i; }
        }
        rv[tid] = bv; rp[tid] = bp;
        __syncthreads();
        for (int off = 128; off > 0; off >>= 1) {
            if (tid < off) {
                if (rv[tid + off] > rv[tid]) { rv[tid] = rv[tid + off]; rp[tid] = rp[tid + off]; }
            }
            __syncthreads();
        }
        if (tid == 0) { widx[pass] = (int)(rv[0] & 0xffffffffu); lc[rp[0]] = 0ull; }
        __syncthreads();
    }
    if (tid < 10) pts[(size_t)b * GV + widx[tid]] = 1.0f;
}

// ---------------------------------------------------------------------------
extern "C" void kernel_launch(void* const* d_in, const int* in_sizes, int n_in,
                              void* d_out, int out_size, void* d_ws, size_t ws_size,
                              hipStream_t stream)
{
    const float* bnd   = (const float*)d_in[0];
    const float* w1    = (const float*)d_in[1];
    const float* b1    = (const float*)d_in[2];
    const float* w2    = (const float*)d_in[3];
    const float* b2    = (const float*)d_in[4];
    const float* fw1   = (const float*)d_in[5];
    const float* fb1   = (const float*)d_in[6];
    const float* fw2   = (const float*)d_in[7];
    const float* fb2   = (const float*)d_in[8];
    const float* noise = (const float*)d_in[9];

    float* out = (float*)d_out;
    char* ws = (char*)d_ws;

    const size_t xbuf_off = 0;                                 // 8 MB
    const size_t pacc_off = xbuf_off + (size_t)NB * GV * 4;    // 512 KB
    const size_t cand_off = pacc_off + (size_t)NB * 64 * 256 * 4;
    const size_t zbuf_off = cand_off + (size_t)NB * BPB * 10 * 8;

    float* xbuf = (float*)(ws + xbuf_off);
    float* pacc = (float*)(ws + pacc_off);
    U64*   cand = (U64*)(ws + cand_off);
    u16*   zbuf = (u16*)(ws + zbuf_off);                       // 8 x 13.5 MB

    dim3 gA(256, NB);       // (4z x 4y) boxes x 8 batches
    convA_mfma_kernel<<<gA, 256, 0, stream>>>(bnd, w1, b1, w2, zbuf);

    dim3 gB(GV / 256, NB);
    convB_kernel<<<gB, 256, 0, stream>>>(zbuf, (size_t)27 * GV, xbuf, (size_t)GV, b2);

    dim3 gfc(32, 64);
    fc1_kernel<<<gfc, 256, 0, stream>>>(fw1, xbuf, pacc);
    fc_final_kernel<<<1, 256, 0, stream>>>(pacc, fb1, fw2, fb2, out + (size_t)NB * GV);

    zero_pts_kernel<<<(NB * GV / 4) / 256, 256, 0, stream>>>((float4*)out);
    dim3 gt(BPB, NB);
    topk1_kernel<<<gt, 256, 0, stream>>>(bnd, noise, cand);
    topk2_kernel<<<NB, 256, 0, stream>>>(cand, out);
}